// Round 6
// baseline (247.544 us; speedup 1.0000x reference)
//
#include <hip/hip_runtime.h>
#include <hip/hip_bf16.h>

#define NN 20000
#define DEG 16
#define KD 512      // IN_DIM
#define OD 512      // OUT_DIM
#define NH 4
#define DH 128
#define DROPE 126

#define BM 128
#define BN 128
#define BK 64       // [128][64] tiles, XOR-swizzled chunks, for global_load_lds

typedef unsigned short u16;
typedef unsigned int u32;
typedef __attribute__((ext_vector_type(8))) short short8;
typedef __attribute__((ext_vector_type(4))) float f32x4;

__device__ __forceinline__ float b2f(u16 u){ return __uint_as_float((u32)u << 16); }
__device__ __forceinline__ u16 f2b(float f){
  u32 x = __float_as_uint(f);
  return (u16)((x + 0x7fffu + ((x >> 16) & 1u)) >> 16);   // RNE
}
__device__ __forceinline__ void up8(uint4 u, float* f){
  f[0]=__uint_as_float(u.x<<16); f[1]=__uint_as_float(u.x&0xffff0000u);
  f[2]=__uint_as_float(u.y<<16); f[3]=__uint_as_float(u.y&0xffff0000u);
  f[4]=__uint_as_float(u.z<<16); f[5]=__uint_as_float(u.z&0xffff0000u);
  f[6]=__uint_as_float(u.w<<16); f[7]=__uint_as_float(u.w&0xffff0000u);
}
__device__ __forceinline__ uint4 cvt8(const float* s){
  uint4 a = *(const uint4*)s;
  uint4 b = *(const uint4*)(s + 4);
  uint4 o;
  o.x = (u32)f2b(__uint_as_float(a.x)) | ((u32)f2b(__uint_as_float(a.y)) << 16);
  o.y = (u32)f2b(__uint_as_float(a.z)) | ((u32)f2b(__uint_as_float(a.w)) << 16);
  o.z = (u32)f2b(__uint_as_float(b.x)) | ((u32)f2b(__uint_as_float(b.y)) << 16);
  o.w = (u32)f2b(__uint_as_float(b.z)) | ((u32)f2b(__uint_as_float(b.w)) << 16);
  return o;
}

// async global->LDS, 16B per lane; LDS dest is wave-uniform base + lane*16
__device__ __forceinline__ void load_lds16(const u16* g, u16* l) {
  __builtin_amdgcn_global_load_lds(
      (const __attribute__((address_space(1))) void*)g,
      (__attribute__((address_space(3))) void*)l, 16, 0, 0);
}

// single fused f32->bf16 conversion pass: x (5000 blocks), W x4 (512), biases (1).
// Wo additionally gets its INPUT columns permuted natural->head-major
// (c' = h*128+d reads c = d*4+h) so the final GEMM can consume a head-major y.
struct ConvJob {
  const float* x;  u16* xb;                  // NN*KD
  const float* w[4]; u16* wb[4];             // OD*KD each
  const float* b[4]; u16* bb[4];             // OD each
};
__global__ __launch_bounds__(256) void conv_all(ConvJob j) {
  const int b = blockIdx.x;
  if (b < 5000) {                            // x: 10.24M elems
    const int i8 = (b * 256 + threadIdx.x) * 8;
    *(uint4*)(j.xb + i8) = cvt8(j.x + i8);
  } else if (b < 5512) {                     // weights: 4 x 262144 elems
    const int t = b - 5000;
    const int wsel = t >> 7;                 // 128 blocks per weight
    const int i8 = ((t & 127) * 256 + threadIdx.x) * 8;
    if (wsel < 3) {
      *(uint4*)(j.wb[wsel] + i8) = cvt8(j.w[wsel] + i8);
    } else {
      // Wo permute: output 8 consecutive head-major cols (h fixed, d0..d0+7)
      const int o = i8 >> 9, cp = i8 & 511;
      const int h = cp >> 7, d0 = cp & 127;
      const float* src = j.w[3] + (size_t)o * 512 + h;
      float tmp[8];
      #pragma unroll
      for (int t2 = 0; t2 < 8; t2++) tmp[t2] = src[(size_t)(d0 + t2) * 4];
      uint4 ov;
      ov.x = (u32)f2b(tmp[0]) | ((u32)f2b(tmp[1]) << 16);
      ov.y = (u32)f2b(tmp[2]) | ((u32)f2b(tmp[3]) << 16);
      ov.z = (u32)f2b(tmp[4]) | ((u32)f2b(tmp[5]) << 16);
      ov.w = (u32)f2b(tmp[6]) | ((u32)f2b(tmp[7]) << 16);
      *(uint4*)(j.wb[3] + i8) = ov;
    }
  } else {                                   // biases: 4 x 512 elems in one block
    const int vsel = threadIdx.x >> 6;
    const int i8 = (threadIdx.x & 63) * 8;
    *(uint4*)(j.bb[vsel] + i8) = cvt8(j.b[vsel] + i8);
  }
}

// QKV projection, W-FOLDED: one block computes the q, k AND v 128x128 tiles
// for its (rowT,colT), sharing a single A-tile stage per K-iter.
// R5 post-mortem: per-K-iter cost is a ~4000cyc fixed stall (load RTT +
// barrier convoy) vs ~1200cyc content at 8 waves/CU; no pipe >30% busy.
// Folding triples per-iter math against the same fixed stall, cuts the grid
// 1884->640 and A-staging 12x->4x. acc = 3x4x4 f32x4 = 192 VGPR (all
// statically indexed); launch_bounds(256,2) caps allocation at 256.
// Staging: 64KB single-buffered [A|B0|B1|B2], XOR-swizzled chunks; epilogue
// Cs (36.9KB) unions onto the dead staging buffer; 2 blocks/CU.
__global__ __launch_bounds__(256, 2) void gemm_k(
    const u16* __restrict__ A,
    const u16* __restrict__ W0, const u16* __restrict__ B0,
    const u16* __restrict__ W1, const u16* __restrict__ B1,
    const u16* __restrict__ W2, const u16* __restrict__ B2,
    const float* __restrict__ pos,          // f32! bf16 pos loses 0.2 rad of RoPE angle
    u16* __restrict__ o0, u16* __restrict__ o1, u16* __restrict__ o2,
    int M)
{
  __shared__ __align__(16) char smem[65536];  // [A 16KB|B0 16KB|B1 16KB|B2 16KB]
  __shared__ float posS[BM*3];
  __shared__ float freqS[21];               // 10000^(-m/21), m=0..20

  const int b = blockIdx.x;
  const int xcd = b & 7, rem = b >> 3;      // 640 blocks: 20 rowT-slots x 4 colT x 8 xcd
  const int rowT = (rem >> 2)*8 + xcd;
  const int colT = rem & 3;
  if (rowT*BM >= M) return;

  const int tid = threadIdx.x;
  const int wave = tid >> 6, lane = tid & 63;
  const int wr = wave >> 1, wc = wave & 1;
  const int lm = lane & 15, lq = lane >> 4;
  const u16* Wp[3] = { W0, W1, W2 };

  f32x4 acc[3][4][4];
  #pragma unroll
  for (int w = 0; w < 3; w++)
    #pragma unroll
    for (int i = 0; i < 4; i++)
      #pragma unroll
      for (int jj = 0; jj < 4; jj++)
        acc[w][i][jj] = (f32x4){0.f, 0.f, 0.f, 0.f};

  // pos/freq staging (covered by first __syncthreads)
  if (tid < BM) {
    int gr = rowT*BM + tid; if (gr >= M) gr = M - 1;
    posS[tid*3+0] = pos[gr*3+0];
    posS[tid*3+1] = pos[gr*3+1];
    posS[tid*3+2] = pos[gr*3+2];
  }
  if (tid >= BM && tid < BM + 21)
    freqS[tid - BM] = __expf(-(float)(tid - BM) * 0.43858763676077064f);

  u16* As = (u16*)smem;

  for (int kt = 0; kt < KD; kt += BK) {
    // stage A + B0/B1/B2: physical chunk c holds global (row=c>>3,
    // seg=(c&7)^(row&7)); ds_read of (row,seg) -> banks spread 8-way.
    #pragma unroll
    for (int it = 0; it < 4; it++) {
      const int chunk = it*256 + tid;              // 0..1023
      const int row = chunk >> 3, gseg = (chunk & 7) ^ (row & 7);
      int gr = rowT*BM + row; if (gr >= M) gr = M - 1;
      load_lds16(A + (size_t)gr*KD + kt + gseg*8,
                 As + (size_t)(it*256 + wave*64)*8);
    }
    #pragma unroll
    for (int w = 0; w < 3; w++) {
      u16* Bsw = (u16*)(smem + (1 + w)*16384);
      #pragma unroll
      for (int it = 0; it < 4; it++) {
        const int chunk = it*256 + tid;
        const int row = chunk >> 3, gseg = (chunk & 7) ^ (row & 7);
        load_lds16(Wp[w] + (size_t)(colT*BN + row)*KD + kt + gseg*8,
                   Bsw + (size_t)(it*256 + wave*64)*8);
      }
    }
    __syncthreads();                  // drains vmcnt (global_load_lds) too
    #pragma unroll
    for (int kk = 0; kk < 2; kk++) {
      const int ks = kk*4;
      short8 af[4];
      #pragma unroll
      for (int i = 0; i < 4; i++) {
        const int ra = wr*64 + i*16 + lm;
        af[i] = *(const short8*)(As + (size_t)(ra*8 + ((ks + lq) ^ (ra & 7)))*8);
      }
      #pragma unroll
      for (int w = 0; w < 3; w++) {
        const u16* Bsw = (const u16*)(smem + (1 + w)*16384);
        short8 bfr[4];
        #pragma unroll
        for (int i = 0; i < 4; i++) {
          const int rb = wc*64 + i*16 + lm;
          bfr[i] = *(const short8*)(Bsw + (size_t)(rb*8 + ((ks + lq) ^ (rb & 7)))*8);
        }
        #pragma unroll
        for (int mi = 0; mi < 4; mi++)
          #pragma unroll
          for (int ni = 0; ni < 4; ni++)
            acc[w][mi][ni] = __builtin_amdgcn_mfma_f32_16x16x32_bf16(af[mi], bfr[ni], acc[w][mi][ni], 0, 0, 0);
      }
    }
    __syncthreads();                  // all waves done reading before restage
  }

  const u16* Bb[3] = { B0, B1, B2 };
  u16* Ob[3] = { o0, o1, o2 };
  u16* Cs = (u16*)smem;   // tiles dead; reused per-weight

  // three epilogues: (scale/rope for q,k; plain v) -> head-major [N][4][128]
  // Cs layout: [rloc 128][h 4][dloc 36(pad)]
  #pragma unroll
  for (int w = 0; w < 3; w++) {
    if (w) __syncthreads();           // Cs reuse: prior stores done
    float bvv[4];
    #pragma unroll
    for (int ni = 0; ni < 4; ni++)
      bvv[ni] = b2f(Bb[w][colT*BN + wc*64 + ni*16 + lm]);
    #pragma unroll
    for (int mi = 0; mi < 4; mi++) {
      #pragma unroll
      for (int ni = 0; ni < 4; ni++) {
        const int cloc = wc*64 + ni*16 + lm;
        const int h = cloc & 3, dloc = cloc >> 2;
        const int d = colT*32 + dloc;
        #pragma unroll
        for (int r = 0; r < 4; r++) {
          const int rloc = wr*64 + mi*16 + lq*4 + r;
          float v = acc[w][mi][ni][r] + bvv[ni];
          if (w == 0) v *= 0.08838834764831845f;  // 1/sqrt(128)
          float vr = v;
          if (w < 2) {                            // uniform branch per w (unrolled)
            const float partner = __shfl_xor(v, 4);  // rope pair: d^1 == lane^4
            if (d < DROPE) {
              const int pp = d / 42, rem2 = d - pp*42, m = rem2 >> 1, par = rem2 & 1;
              const float ang = posS[rloc*3 + pp] * freqS[m];
              float sn, cs; __sincosf(ang, &sn, &cs);
              vr = par ? (v*cs + partner*sn) : (v*cs - partner*sn);
            }
          }
          Cs[rloc*144 + h*36 + dloc] = f2b(vr);
        }
      }
    }
    __syncthreads();
    #pragma unroll
    for (int pass = 0; pass < 8; pass++) {
      const int c2 = pass*256 + tid;              // 0..2047
      const int dd8 = c2 & 3, h = (c2 >> 2) & 3, rloc = c2 >> 4;
      const int grow = rowT*BM + rloc;
      if (grow < M) {
        uint2 a = *(const uint2*)(Cs + rloc*144 + h*36 + dd8*8);
        uint2 b2 = *(const uint2*)(Cs + rloc*144 + h*36 + dd8*8 + 4);
        *(uint4*)(Ob[w] + ((size_t)grow*NH + h)*DH + colT*32 + dd8*8)
            = make_uint4(a.x, a.y, b2.x, b2.y);
      }
    }
  }
}

// Out-projection GEMM: y(bf16, head-major-flattened) @ Wo(perm)^T + bo -> f32.
// Single-buffered 32KB LDS, no pos/rope/repack, launch_bounds(256,4) ->
// all 640 blocks co-resident.
__global__ __launch_bounds__(256, 4) void gemm_o(
    const u16* __restrict__ A, const u16* __restrict__ W,
    const u16* __restrict__ Bi, float* __restrict__ out, int M)
{
  __shared__ __align__(16) u16 As[BM*BK];   // [128 rows][8 chunks], XOR-swizzled
  __shared__ __align__(16) u16 Bs[BN*BK];

  const int b = blockIdx.x;
  const int xcd = b & 7, rem = b >> 3;
  const int rowT = (rem >> 2)*8 + xcd, colT = rem & 3;
  if (rowT*BM >= M) return;

  const int tid = threadIdx.x;
  const int wave = tid >> 6, lane = tid & 63;
  const int wr = wave >> 1, wc = wave & 1;
  const int lm = lane & 15, lq = lane >> 4;

  f32x4 acc[4][4];
  #pragma unroll
  for (int i = 0; i < 4; i++)
    #pragma unroll
    for (int jj = 0; jj < 4; jj++)
      acc[i][jj] = (f32x4){0.f, 0.f, 0.f, 0.f};

  for (int kt = 0; kt < KD; kt += BK) {
    #pragma unroll
    for (int it = 0; it < 4; it++) {
      const int chunk = it*256 + tid;              // 0..1023
      const int row = chunk >> 3, gseg = (chunk & 7) ^ (row & 7);
      int gr = rowT*BM + row; if (gr >= M) gr = M - 1;
      load_lds16(A + (size_t)gr*KD + kt + gseg*8,
                 As + (size_t)(it*256 + wave*64)*8);
    }
    #pragma unroll
    for (int it = 0; it < 4; it++) {
      const int chunk = it*256 + tid;
      const int row = chunk >> 3, gseg = (chunk & 7) ^ (row & 7);
      load_lds16(W + (size_t)(colT*BN + row)*KD + kt + gseg*8,
                 Bs + (size_t)(it*256 + wave*64)*8);
    }
    __syncthreads();                  // drains vmcnt (global_load_lds) too
    #pragma unroll
    for (int kk = 0; kk < BK; kk += 32) {
      const int ks = kk >> 3;                      // 0 or 4
      short8 af[4], bfr[4];
      #pragma unroll
      for (int i = 0; i < 4; i++) {
        const int ra = wr*64 + i*16 + lm;
        af[i] = *(const short8*)(As + (size_t)(ra*8 + ((ks + lq) ^ (ra & 7)))*8);
      }
      #pragma unroll
      for (int i = 0; i < 4; i++) {
        const int rb = wc*64 + i*16 + lm;
        bfr[i] = *(const short8*)(Bs + (size_t)(rb*8 + ((ks + lq) ^ (rb & 7)))*8);
      }
      #pragma unroll
      for (int mi = 0; mi < 4; mi++)
        #pragma unroll
        for (int ni = 0; ni < 4; ni++)
          acc[mi][ni] = __builtin_amdgcn_mfma_f32_16x16x32_bf16(af[mi], bfr[ni], acc[mi][ni], 0, 0, 0);
    }
    __syncthreads();
  }

  float bvv[4];
  #pragma unroll
  for (int ni = 0; ni < 4; ni++)
    bvv[ni] = b2f(Bi[colT*BN + wc*64 + ni*16 + lm]);

  // direct f32 stores; 64B segments per lq-group
  #pragma unroll
  for (int mi = 0; mi < 4; mi++)
    #pragma unroll
    for (int ni = 0; ni < 4; ni++) {
      const int Cg = colT*BN + wc*64 + ni*16 + lm;
      #pragma unroll
      for (int r = 0; r < 4; r++) {
        const int grow = rowT*BM + wr*64 + mi*16 + lq*4 + r;
        if (grow < M) out[(size_t)grow*OD + Cg] = acc[mi][ni][r] + bvv[ni];
      }
    }
}

// TWO-PASS head-partitioned edge attention (R5: both passes out of top-5).
// Head-partition: per-XCD hot set k_h or v_h ~5-8MB, near-L2-resident.
// Same (node,head)->XCD mapping in both passes keeps locality consistent.

// pass 1: scores + softmax -> attn weights f32 [N][H][DEG]
__global__ __launch_bounds__(256, 3) void edge_score(
    const int* __restrict__ cols, const u16* __restrict__ qf,
    const u16* __restrict__ kf, float* __restrict__ aw)
{
  const int b = blockIdx.x;
  const int xcd = b & 7;
  const int head = xcd >> 1;
  const int nbase = (b >> 3) * 32 + (xcd & 1) * 16;   // block: 16 nodes, 1 head
  const int wave = threadIdx.x >> 6, lane = threadIdx.x & 63;
  const int g = lane >> 4, l16 = lane & 15;
  const int n = nbase + wave*4 + g;

  const int col = cols[n*DEG + l16];                  // 256B/wave, coalesced
  const uint4 qv = *(const uint4*)(qf + ((size_t)n*NH + head)*DH + l16*8);

  // 16 coalesced 256B k-row loads (per 16-lane group), oldest first
  uint4 kreg[16];
  #pragma unroll
  for (int jj = 0; jj < 16; jj++) {
    const int cj = __shfl(col, g*16 + jj);
    kreg[jj] = *(const uint4*)(kf + ((size_t)cj*NH + head)*DH + l16*8);
  }
  float qa[8]; up8(qv, qa);

  // scores: lane l16 ends holding s[neighbor l16]
  float s = 0.f;
  #pragma unroll
  for (int jj = 0; jj < 16; jj++) {
    float ka[8]; up8(kreg[jj], ka);
    float pr = qa[0]*ka[0] + qa[1]*ka[1] + qa[2]*ka[2] + qa[3]*ka[3]
             + qa[4]*ka[4] + qa[5]*ka[5] + qa[6]*ka[6] + qa[7]*ka[7];
    pr += __shfl_xor(pr, 1);
    pr += __shfl_xor(pr, 2);
    pr += __shfl_xor(pr, 4);
    pr += __shfl_xor(pr, 8);          // full 128-d dot, within the 16-lane group
    s = (l16 == jj) ? pr : s;
  }

  // softmax over the group's 16 lanes
  float mx = s;
  #pragma unroll
  for (int msk = 1; msk < 16; msk <<= 1) mx = fmaxf(mx, __shfl_xor(mx, msk));
  float p = expf(s - mx);
  float dn = p;
  #pragma unroll
  for (int msk = 1; msk < 16; msk <<= 1) dn += __shfl_xor(dn, msk);
  aw[(size_t)(n*NH + head)*DEG + l16] = p / dn;       // 64B per group
}

// pass 2: y[n][h] = sum_j attn[j] * v[col_j][h]
__global__ __launch_bounds__(256, 3) void edge_gather(
    const int* __restrict__ cols, const u16* __restrict__ vf,
    const float* __restrict__ aw, u16* __restrict__ y)
{
  const int b = blockIdx.x;
  const int xcd = b & 7;
  const int head = xcd >> 1;
  const int nbase = (b >> 3) * 32 + (xcd & 1) * 16;
  const int wave = threadIdx.x >> 6, lane = threadIdx.x & 63;
  const int g = lane >> 4, l16 = lane & 15;
  const int n = nbase + wave*4 + g;

  const int col = cols[n*DEG + l16];
  const float a_l = aw[(size_t)(n*NH + head)*DEG + l16];

  uint4 vreg[16];
  #pragma unroll
  for (int jj = 0; jj < 16; jj++) {
    const int cj = __shfl(col, g*16 + jj);
    vreg[jj] = *(const uint4*)(vf + ((size_t)cj*NH + head)*DH + l16*8);
  }

  float ya[8];
  #pragma unroll
  for (int t = 0; t < 8; t++) ya[t] = 0.f;
  #pragma unroll
  for (int jj = 0; jj < 16; jj++) {
    const float a = __shfl(a_l, g*16 + jj);
    float va[8]; up8(vreg[jj], va);
    #pragma unroll
    for (int t = 0; t < 8; t++) ya[t] += a*va[t];
  }
  u32 pk[4];
  #pragma unroll
  for (int t = 0; t < 4; t++)
    pk[t] = (u32)f2b(ya[2*t]) | ((u32)f2b(ya[2*t+1]) << 16);
  *(uint4*)(y + ((size_t)n*NH + head)*DH + l16*8) = make_uint4(pk[0], pk[1], pk[2], pk[3]);
}

extern "C" void kernel_launch(void* const* d_in, const int* in_sizes, int n_in,
                              void* d_out, int out_size, void* d_ws, size_t ws_size,
                              hipStream_t stream) {
  (void)in_sizes; (void)n_in; (void)out_size; (void)ws_size;
  const float* x   = (const float*)d_in[0];
  const float* pos = (const float*)d_in[1];
  // d_in[2] = rows: sorted repeat(arange(N), DEG) — structure used implicitly
  const int* cols = (const int*)d_in[3];
  const float* Wq = (const float*)d_in[4];
  const float* bq = (const float*)d_in[5];
  const float* Wk = (const float*)d_in[6];
  const float* bk = (const float*)d_in[7];
  const float* Wv = (const float*)d_in[8];
  const float* bv = (const float*)d_in[9];
  const float* Wo = (const float*)d_in[10];
  const float* bo = (const float*)d_in[11];

  char* ws = (char*)d_ws;
  size_t off = 0;
  auto carve = [&](size_t bytes) { char* p = ws + off; off += (bytes + 15) & ~(size_t)15; return p; };
  u16* xb   = (u16*)carve((size_t)NN*KD*2);
  u16* Wqb  = (u16*)carve((size_t)OD*KD*2);
  u16* Wkb  = (u16*)carve((size_t)OD*KD*2);
  u16* Wvb  = (u16*)carve((size_t)OD*KD*2);
  u16* Wob  = (u16*)carve((size_t)OD*OD*2);
  u16* bqb  = (u16*)carve((size_t)OD*2);
  u16* bkb  = (u16*)carve((size_t)OD*2);
  u16* bvb  = (u16*)carve((size_t)OD*2);
  u16* bob  = (u16*)carve((size_t)OD*2);
  u16* qf   = (u16*)carve((size_t)NN*OD*2);
  u16* kf   = (u16*)carve((size_t)NN*OD*2);
  u16* vf   = (u16*)carve((size_t)NN*OD*2);
  u16* y    = (u16*)carve((size_t)NN*OD*2);
  float* aw = (float*)carve((size_t)NN*NH*DEG*4);     // attn weights [N][H][DEG]

  ConvJob cj;
  cj.x = x; cj.xb = xb;
  cj.w[0]=Wq; cj.w[1]=Wk; cj.w[2]=Wv; cj.w[3]=Wo;
  cj.wb[0]=Wqb; cj.wb[1]=Wkb; cj.wb[2]=Wvb; cj.wb[3]=Wob;
  cj.b[0]=bq; cj.b[1]=bk; cj.b[2]=bv; cj.b[3]=bo;
  cj.bb[0]=bqb; cj.bb[1]=bkb; cj.bb[2]=bvb; cj.bb[3]=bob;
  conv_all<<<dim3(5513), 256, 0, stream>>>(cj);

  // QKV w-folded: 8 xcd * 20 rowT-slots * 4 colT = 640 blocks (12 early-return)
  gemm_k<<<dim3(640), 256, 0, stream>>>(xb, Wqb, bqb, Wkb, bkb, Wvb, bvb, pos,
                                        qf, kf, vf, NN);
  // two-pass attention: 625 node-chunks * 8 xcd = 5000 blocks each
  edge_score<<<dim3(5000), 256, 0, stream>>>(cols, qf, kf, aw);
  edge_gather<<<dim3(5000), 256, 0, stream>>>(cols, vf, aw, y);
  // out: 8 * 20 * 4 = 640 blocks; Wob has head-major-permuted input cols
  gemm_o<<<dim3(640), 256, 0, stream>>>(y, Wob, bob, (float*)d_out, NN);
}

// Round 9
// 244.433 us; speedup vs baseline: 1.0127x; 1.0127x over previous
//
#include <hip/hip_runtime.h>
#include <hip/hip_bf16.h>

#define NN 20000
#define DEG 16
#define KD 512      // IN_DIM
#define OD 512      // OUT_DIM
#define NH 4
#define DH 128
#define DROPE 126

#define BM 128
#define BN 128

typedef unsigned short u16;
typedef unsigned int u32;
typedef __attribute__((ext_vector_type(8))) short short8;
typedef __attribute__((ext_vector_type(4))) float f32x4;

__device__ __forceinline__ float b2f(u16 u){ return __uint_as_float((u32)u << 16); }
__device__ __forceinline__ u16 f2b(float f){
  u32 x = __float_as_uint(f);
  return (u16)((x + 0x7fffu + ((x >> 16) & 1u)) >> 16);   // RNE
}
__device__ __forceinline__ void up8(uint4 u, float* f){
  f[0]=__uint_as_float(u.x<<16); f[1]=__uint_as_float(u.x&0xffff0000u);
  f[2]=__uint_as_float(u.y<<16); f[3]=__uint_as_float(u.y&0xffff0000u);
  f[4]=__uint_as_float(u.z<<16); f[5]=__uint_as_float(u.z&0xffff0000u);
  f[6]=__uint_as_float(u.w<<16); f[7]=__uint_as_float(u.w&0xffff0000u);
}
__device__ __forceinline__ uint4 cvt8(const float* s){
  uint4 a = *(const uint4*)s;
  uint4 b = *(const uint4*)(s + 4);
  uint4 o;
  o.x = (u32)f2b(__uint_as_float(a.x)) | ((u32)f2b(__uint_as_float(a.y)) << 16);
  o.y = (u32)f2b(__uint_as_float(a.z)) | ((u32)f2b(__uint_as_float(a.w)) << 16);
  o.z = (u32)f2b(__uint_as_float(b.x)) | ((u32)f2b(__uint_as_float(b.y)) << 16);
  o.w = (u32)f2b(__uint_as_float(b.z)) | ((u32)f2b(__uint_as_float(b.w)) << 16);
  return o;
}

// async global->LDS, 16B per lane; LDS dest is wave-uniform base + lane*16
__device__ __forceinline__ void load_lds16(const u16* g, u16* l) {
  __builtin_amdgcn_global_load_lds(
      (const __attribute__((address_space(1))) void*)g,
      (__attribute__((address_space(3))) void*)l, 16, 0, 0);
}

// single fused f32->bf16 conversion pass: x (5000 blocks), W x4 (512), biases (1).
// Wo additionally gets its INPUT columns permuted natural->head-major
// (c' = h*128+d reads c = d*4+h) so the final GEMM can consume a head-major y.
struct ConvJob {
  const float* x;  u16* xb;                  // NN*KD
  const float* w[4]; u16* wb[4];             // OD*KD each
  const float* b[4]; u16* bb[4];             // OD each
};
__global__ __launch_bounds__(256) void conv_all(ConvJob j) {
  const int b = blockIdx.x;
  if (b < 5000) {                            // x: 10.24M elems
    const int i8 = (b * 256 + threadIdx.x) * 8;
    *(uint4*)(j.xb + i8) = cvt8(j.x + i8);
  } else if (b < 5512) {                     // weights: 4 x 262144 elems
    const int t = b - 5000;
    const int wsel = t >> 7;                 // 128 blocks per weight
    const int i8 = ((t & 127) * 256 + threadIdx.x) * 8;
    if (wsel < 3) {
      *(uint4*)(j.wb[wsel] + i8) = cvt8(j.w[wsel] + i8);
    } else {
      // Wo permute: output 8 consecutive head-major cols (h fixed, d0..d0+7)
      const int o = i8 >> 9, cp = i8 & 511;
      const int h = cp >> 7, d0 = cp & 127;
      const float* src = j.w[3] + (size_t)o * 512 + h;
      float tmp[8];
      #pragma unroll
      for (int t2 = 0; t2 < 8; t2++) tmp[t2] = src[(size_t)(d0 + t2) * 4];
      uint4 ov;
      ov.x = (u32)f2b(tmp[0]) | ((u32)f2b(tmp[1]) << 16);
      ov.y = (u32)f2b(tmp[2]) | ((u32)f2b(tmp[3]) << 16);
      ov.z = (u32)f2b(tmp[4]) | ((u32)f2b(tmp[5]) << 16);
      ov.w = (u32)f2b(tmp[6]) | ((u32)f2b(tmp[7]) << 16);
      *(uint4*)(j.wb[3] + i8) = ov;
    }
  } else {                                   // biases: 4 x 512 elems in one block
    const int vsel = threadIdx.x >> 6;
    const int i8 = (threadIdx.x & 63) * 8;
    *(uint4*)(j.bb[vsel] + i8) = cvt8(j.b[vsel] + i8);
  }
}

// QKV projection. out[m][o] = sum_k A[m][k]*W[o][k] + bias[o]
// emode 0: q -> scale + rope -> head-major [N][H][DH] bf16 (o0)
// emode 1: k -> rope -> head-major (o1)
// emode 2: v -> head-major, no rope/scale (o2)
// R6 post-mortem: W-folding spilled (VGPR capped 128 vs 192-reg acc) ->
// REVERTED to per-w blocks. This round: BK=128 (4 K-iters instead of 8).
// The kernel is latency-bound (no pipe >31% busy): per-iter cost ~= fixed
// stall (stage RTT + barrier convoy) + content. Same 4x4 acc (64 VGPR, no
// spill), same 2 blocks/CU (A 32K + B 32K = 64KB), but HALF the stalls.
// Swizzle: 16 chunks/row, phys chunk c holds global seg (c&15)^(row&15);
// fragment read of (row,seg) at phys (seg^(row&15)) — b128-minimum aliasing.
__global__ __launch_bounds__(256, 2) void gemm_k(
    const u16* __restrict__ A,
    const u16* __restrict__ W0, const u16* __restrict__ B0,
    const u16* __restrict__ W1, const u16* __restrict__ B1,
    const u16* __restrict__ W2, const u16* __restrict__ B2,
    const float* __restrict__ pos,          // f32! bf16 pos loses 0.2 rad of RoPE angle
    u16* __restrict__ o0, u16* __restrict__ o1, u16* __restrict__ o2,
    int M)
{
  __shared__ __align__(16) char smem[65536];  // [A 32KB | B 32KB], BK=128
  __shared__ float posS[BM*3];
  __shared__ float freqS[21];               // 10000^(-m/21), m=0..20
  u16* As = (u16*)smem;
  u16* Bs = As + BM*128;

  const int b = blockIdx.x;
  const int xcd = b & 7, rem = b >> 3;      // 1920 blocks: 20 rowT x 4 colT x 3 w x 8 xcd
  const int rowT = (rem / 12)*8 + xcd;
  const int sub = rem % 12;
  const int colT = sub & 3, w = sub >> 2;
  if (rowT*BM >= M) return;

  const int tid = threadIdx.x;
  const int wave = tid >> 6, lane = tid & 63;
  const int wr = wave >> 1, wc = wave & 1;
  const int lm = lane & 15, lq = lane >> 4;
  const u16* W  = (w == 0) ? W0 : ((w == 1) ? W1 : W2);
  const u16* Bi = (w == 0) ? B0 : ((w == 1) ? B1 : B2);
  const int emode = w;                      // uniform per block
  u16* outQKV = (w == 0) ? o0 : ((w == 1) ? o1 : o2);

  f32x4 acc[4][4];
  #pragma unroll
  for (int i = 0; i < 4; i++)
    #pragma unroll
    for (int jj = 0; jj < 4; jj++)
      acc[i][jj] = (f32x4){0.f, 0.f, 0.f, 0.f};

  // pos/freq staging (covered by first __syncthreads)
  if (emode < 2) {
    if (tid < BM) {
      int gr = rowT*BM + tid; if (gr >= M) gr = M - 1;
      posS[tid*3+0] = pos[gr*3+0];
      posS[tid*3+1] = pos[gr*3+1];
      posS[tid*3+2] = pos[gr*3+2];
    }
    if (tid >= BM && tid < BM + 21)
      freqS[tid - BM] = __expf(-(float)(tid - BM) * 0.43858763676077064f);
  }

  for (int kt = 0; kt < KD; kt += 128) {
    // stage A/B tile [128 rows][16 chunks of 8 bf16], chunk-XOR-swizzled.
    // 2048 chunks each -> 8 gload_lds per thread per tile.
    #pragma unroll
    for (int it = 0; it < 8; it++) {
      const int chunk = it*256 + wave*64 + lane;     // 0..2047
      const int row = chunk >> 4, gseg = (chunk & 15) ^ (row & 15);
      int gr = rowT*BM + row; if (gr >= M) gr = M - 1;
      load_lds16(A + (size_t)gr*KD + kt + gseg*8,
                 As + (size_t)(it*256 + wave*64)*8);
    }
    #pragma unroll
    for (int it = 0; it < 8; it++) {
      const int chunk = it*256 + wave*64 + lane;
      const int row = chunk >> 4, gseg = (chunk & 15) ^ (row & 15);
      load_lds16(W + (size_t)(colT*BN + row)*KD + kt + gseg*8,
                 Bs + (size_t)(it*256 + wave*64)*8);
    }
    __syncthreads();                  // drains vmcnt (global_load_lds) too
    #pragma unroll
    for (int kk = 0; kk < 128; kk += 32) {
      const int ks = kk >> 3;                        // 0,4,8,12
      short8 af[4], bfr[4];
      #pragma unroll
      for (int i = 0; i < 4; i++) {
        const int ra = wr*64 + i*16 + lm;
        af[i] = *(const short8*)(As + (size_t)(ra*16 + ((ks + lq) ^ (ra & 15)))*8);
      }
      #pragma unroll
      for (int i = 0; i < 4; i++) {
        const int rb = wc*64 + i*16 + lm;
        bfr[i] = *(const short8*)(Bs + (size_t)(rb*16 + ((ks + lq) ^ (rb & 15)))*8);
      }
      #pragma unroll
      for (int mi = 0; mi < 4; mi++)
        #pragma unroll
        for (int ni = 0; ni < 4; ni++)
          acc[mi][ni] = __builtin_amdgcn_mfma_f32_16x16x32_bf16(af[mi], bfr[ni], acc[mi][ni], 0, 0, 0);
    }
    __syncthreads();                  // all waves done reading before restage
  }

  float bvv[4];
  #pragma unroll
  for (int ni = 0; ni < 4; ni++)
    bvv[ni] = b2f(Bi[colT*BN + wc*64 + ni*16 + lm]);

  u16* Cs = (u16*)smem;   // tiles dead after final barrier

  // emodes 0/1/2: (scale/rope for q,k) then repack to head-major [N][4][128]
  // Cs layout: [rloc 128][h 4][dloc 36(pad)]
  #pragma unroll
  for (int mi = 0; mi < 4; mi++) {
    #pragma unroll
    for (int ni = 0; ni < 4; ni++) {
      const int cloc = wc*64 + ni*16 + lm;
      const int h = cloc & 3, dloc = cloc >> 2;
      const int d = colT*32 + dloc;
      #pragma unroll
      for (int r = 0; r < 4; r++) {
        const int rloc = wr*64 + mi*16 + lq*4 + r;
        float v = acc[mi][ni][r] + bvv[ni];
        if (emode == 0) v *= 0.08838834764831845f;  // 1/sqrt(128)
        float vr = v;
        if (emode < 2) {                            // uniform branch per block
          const float partner = __shfl_xor(v, 4);   // rope pair: d ^ 1 == lane ^ 4
          if (d < DROPE) {
            const int pp = d / 42, rem2 = d - pp*42, m = rem2 >> 1, par = rem2 & 1;
            const float ang = posS[rloc*3 + pp] * freqS[m];
            float sn, cs; __sincosf(ang, &sn, &cs);
            vr = par ? (v*cs + partner*sn) : (v*cs - partner*sn);
          }
        }
        Cs[rloc*144 + h*36 + dloc] = f2b(vr);
      }
    }
  }
  __syncthreads();
  #pragma unroll
  for (int pass = 0; pass < 8; pass++) {
    const int c2 = pass*256 + tid;              // 0..2047
    const int dd8 = c2 & 3, h = (c2 >> 2) & 3, rloc = c2 >> 4;
    const int grow = rowT*BM + rloc;
    if (grow < M) {
      uint2 a = *(const uint2*)(Cs + rloc*144 + h*36 + dd8*8);
      uint2 b2 = *(const uint2*)(Cs + rloc*144 + h*36 + dd8*8 + 4);
      *(uint4*)(outQKV + ((size_t)grow*NH + h)*DH + colT*32 + dd8*8)
          = make_uint4(a.x, a.y, b2.x, b2.y);
    }
  }
}

// Out-projection GEMM: y(bf16, head-major-flattened) @ Wo(perm)^T + bo -> f32.
// Single-buffered 32KB LDS (BK=64), no pos/rope/repack, launch_bounds(256,4)
// -> all 640 blocks co-resident.
__global__ __launch_bounds__(256, 4) void gemm_o(
    const u16* __restrict__ A, const u16* __restrict__ W,
    const u16* __restrict__ Bi, float* __restrict__ out, int M)
{
  __shared__ __align__(16) u16 As[BM*64];   // [128 rows][8 chunks], XOR-swizzled
  __shared__ __align__(16) u16 Bs[BN*64];

  const int b = blockIdx.x;
  const int xcd = b & 7, rem = b >> 3;
  const int rowT = (rem >> 2)*8 + xcd, colT = rem & 3;
  if (rowT*BM >= M) return;

  const int tid = threadIdx.x;
  const int wave = tid >> 6, lane = tid & 63;
  const int wr = wave >> 1, wc = wave & 1;
  const int lm = lane & 15, lq = lane >> 4;

  f32x4 acc[4][4];
  #pragma unroll
  for (int i = 0; i < 4; i++)
    #pragma unroll
    for (int jj = 0; jj < 4; jj++)
      acc[i][jj] = (f32x4){0.f, 0.f, 0.f, 0.f};

  for (int kt = 0; kt < KD; kt += 64) {
    #pragma unroll
    for (int it = 0; it < 4; it++) {
      const int chunk = it*256 + wave*64 + lane;     // 0..1023
      const int row = chunk >> 3, gseg = (chunk & 7) ^ (row & 7);
      int gr = rowT*BM + row; if (gr >= M) gr = M - 1;
      load_lds16(A + (size_t)gr*KD + kt + gseg*8,
                 As + (size_t)(it*256 + wave*64)*8);
    }
    #pragma unroll
    for (int it = 0; it < 4; it++) {
      const int chunk = it*256 + wave*64 + lane;
      const int row = chunk >> 3, gseg = (chunk & 7) ^ (row & 7);
      load_lds16(W + (size_t)(colT*BN + row)*KD + kt + gseg*8,
                 Bs + (size_t)(it*256 + wave*64)*8);
    }
    __syncthreads();                  // drains vmcnt (global_load_lds) too
    #pragma unroll
    for (int kk = 0; kk < 64; kk += 32) {
      const int ks = kk >> 3;                      // 0 or 4
      short8 af[4], bfr[4];
      #pragma unroll
      for (int i = 0; i < 4; i++) {
        const int ra = wr*64 + i*16 + lm;
        af[i] = *(const short8*)(As + (size_t)(ra*8 + ((ks + lq) ^ (ra & 7)))*8);
      }
      #pragma unroll
      for (int i = 0; i < 4; i++) {
        const int rb = wc*64 + i*16 + lm;
        bfr[i] = *(const short8*)(Bs + (size_t)(rb*8 + ((ks + lq) ^ (rb & 7)))*8);
      }
      #pragma unroll
      for (int mi = 0; mi < 4; mi++)
        #pragma unroll
        for (int ni = 0; ni < 4; ni++)
          acc[mi][ni] = __builtin_amdgcn_mfma_f32_16x16x32_bf16(af[mi], bfr[ni], acc[mi][ni], 0, 0, 0);
    }
    __syncthreads();
  }

  float bvv[4];
  #pragma unroll
  for (int ni = 0; ni < 4; ni++)
    bvv[ni] = b2f(Bi[colT*BN + wc*64 + ni*16 + lm]);

  // direct f32 stores; 64B segments per lq-group
  #pragma unroll
  for (int mi = 0; mi < 4; mi++)
    #pragma unroll
    for (int ni = 0; ni < 4; ni++) {
      const int Cg = colT*BN + wc*64 + ni*16 + lm;
      #pragma unroll
      for (int r = 0; r < 4; r++) {
        const int grow = rowT*BM + wr*64 + mi*16 + lq*4 + r;
        if (grow < M) out[(size_t)grow*OD + Cg] = acc[mi][ni][r] + bvv[ni];
      }
    }
}

// TWO-PASS head-partitioned edge attention (R5: both passes out of top-5).
// Head-partition: per-XCD hot set k_h or v_h ~5-8MB, near-L2-resident.
// Same (node,head)->XCD mapping in both passes keeps locality consistent.

// pass 1: scores + softmax -> attn weights f32 [N][H][DEG]
__global__ __launch_bounds__(256, 3) void edge_score(
    const int* __restrict__ cols, const u16* __restrict__ qf,
    const u16* __restrict__ kf, float* __restrict__ aw)
{
  const int b = blockIdx.x;
  const int xcd = b & 7;
  const int head = xcd >> 1;
  const int nbase = (b >> 3) * 32 + (xcd & 1) * 16;   // block: 16 nodes, 1 head
  const int wave = threadIdx.x >> 6, lane = threadIdx.x & 63;
  const int g = lane >> 4, l16 = lane & 15;
  const int n = nbase + wave*4 + g;

  const int col = cols[n*DEG + l16];                  // 256B/wave, coalesced
  const uint4 qv = *(const uint4*)(qf + ((size_t)n*NH + head)*DH + l16*8);

  // 16 coalesced 256B k-row loads (per 16-lane group), oldest first
  uint4 kreg[16];
  #pragma unroll
  for (int jj = 0; jj < 16; jj++) {
    const int cj = __shfl(col, g*16 + jj);
    kreg[jj] = *(const uint4*)(kf + ((size_t)cj*NH + head)*DH + l16*8);
  }
  float qa[8]; up8(qv, qa);

  // scores: lane l16 ends holding s[neighbor l16]
  float s = 0.f;
  #pragma unroll
  for (int jj = 0; jj < 16; jj++) {
    float ka[8]; up8(kreg[jj], ka);
    float pr = qa[0]*ka[0] + qa[1]*ka[1] + qa[2]*ka[2] + qa[3]*ka[3]
             + qa[4]*ka[4] + qa[5]*ka[5] + qa[6]*ka[6] + qa[7]*ka[7];
    pr += __shfl_xor(pr, 1);
    pr += __shfl_xor(pr, 2);
    pr += __shfl_xor(pr, 4);
    pr += __shfl_xor(pr, 8);          // full 128-d dot, within the 16-lane group
    s = (l16 == jj) ? pr : s;
  }

  // softmax over the group's 16 lanes
  float mx = s;
  #pragma unroll
  for (int msk = 1; msk < 16; msk <<= 1) mx = fmaxf(mx, __shfl_xor(mx, msk));
  float p = expf(s - mx);
  float dn = p;
  #pragma unroll
  for (int msk = 1; msk < 16; msk <<= 1) dn += __shfl_xor(dn, msk);
  aw[(size_t)(n*NH + head)*DEG + l16] = p / dn;       // 64B per group
}

// pass 2: y[n][h] = sum_j attn[j] * v[col_j][h]
__global__ __launch_bounds__(256, 3) void edge_gather(
    const int* __restrict__ cols, const u16* __restrict__ vf,
    const float* __restrict__ aw, u16* __restrict__ y)
{
  const int b = blockIdx.x;
  const int xcd = b & 7;
  const int head = xcd >> 1;
  const int nbase = (b >> 3) * 32 + (xcd & 1) * 16;
  const int wave = threadIdx.x >> 6, lane = threadIdx.x & 63;
  const int g = lane >> 4, l16 = lane & 15;
  const int n = nbase + wave*4 + g;

  const int col = cols[n*DEG + l16];
  const float a_l = aw[(size_t)(n*NH + head)*DEG + l16];

  uint4 vreg[16];
  #pragma unroll
  for (int jj = 0; jj < 16; jj++) {
    const int cj = __shfl(col, g*16 + jj);
    vreg[jj] = *(const uint4*)(vf + ((size_t)cj*NH + head)*DH + l16*8);
  }

  float ya[8];
  #pragma unroll
  for (int t = 0; t < 8; t++) ya[t] = 0.f;
  #pragma unroll
  for (int jj = 0; jj < 16; jj++) {
    const float a = __shfl(a_l, g*16 + jj);
    float va[8]; up8(vreg[jj], va);
    #pragma unroll
    for (int t = 0; t < 8; t++) ya[t] += a*va[t];
  }
  u32 pk[4];
  #pragma unroll
  for (int t = 0; t < 4; t++)
    pk[t] = (u32)f2b(ya[2*t]) | ((u32)f2b(ya[2*t+1]) << 16);
  *(uint4*)(y + ((size_t)n*NH + head)*DH + l16*8) = make_uint4(pk[0], pk[1], pk[2], pk[3]);
}

extern "C" void kernel_launch(void* const* d_in, const int* in_sizes, int n_in,
                              void* d_out, int out_size, void* d_ws, size_t ws_size,
                              hipStream_t stream) {
  (void)in_sizes; (void)n_in; (void)out_size; (void)ws_size;
  const float* x   = (const float*)d_in[0];
  const float* pos = (const float*)d_in[1];
  // d_in[2] = rows: sorted repeat(arange(N), DEG) — structure used implicitly
  const int* cols = (const int*)d_in[3];
  const float* Wq = (const float*)d_in[4];
  const float* bq = (const float*)d_in[5];
  const float* Wk = (const float*)d_in[6];
  const float* bk = (const float*)d_in[7];
  const float* Wv = (const float*)d_in[8];
  const float* bv = (const float*)d_in[9];
  const float* Wo = (const float*)d_in[10];
  const float* bo = (const float*)d_in[11];

  char* ws = (char*)d_ws;
  size_t off = 0;
  auto carve = [&](size_t bytes) { char* p = ws + off; off += (bytes + 15) & ~(size_t)15; return p; };
  u16* xb   = (u16*)carve((size_t)NN*KD*2);
  u16* Wqb  = (u16*)carve((size_t)OD*KD*2);
  u16* Wkb  = (u16*)carve((size_t)OD*KD*2);
  u16* Wvb  = (u16*)carve((size_t)OD*KD*2);
  u16* Wob  = (u16*)carve((size_t)OD*OD*2);
  u16* bqb  = (u16*)carve((size_t)OD*2);
  u16* bkb  = (u16*)carve((size_t)OD*2);
  u16* bvb  = (u16*)carve((size_t)OD*2);
  u16* bob  = (u16*)carve((size_t)OD*2);
  u16* qf   = (u16*)carve((size_t)NN*OD*2);
  u16* kf   = (u16*)carve((size_t)NN*OD*2);
  u16* vf   = (u16*)carve((size_t)NN*OD*2);
  u16* y    = (u16*)carve((size_t)NN*OD*2);
  float* aw = (float*)carve((size_t)NN*NH*DEG*4);     // attn weights [N][H][DEG]

  ConvJob cj;
  cj.x = x; cj.xb = xb;
  cj.w[0]=Wq; cj.w[1]=Wk; cj.w[2]=Wv; cj.w[3]=Wo;
  cj.wb[0]=Wqb; cj.wb[1]=Wkb; cj.wb[2]=Wvb; cj.wb[3]=Wob;
  cj.b[0]=bq; cj.b[1]=bk; cj.b[2]=bv; cj.b[3]=bo;
  cj.bb[0]=bqb; cj.bb[1]=bkb; cj.bb[2]=bvb; cj.bb[3]=bob;
  conv_all<<<dim3(5513), 256, 0, stream>>>(cj);

  // QKV: 8 xcd * 20 rowT-slots * 12 (colT,w) = 1920 blocks (36 early-return)
  gemm_k<<<dim3(1920), 256, 0, stream>>>(xb, Wqb, bqb, Wkb, bkb, Wvb, bvb, pos,
                                         qf, kf, vf, NN);
  // two-pass attention: 625 node-chunks * 8 xcd = 5000 blocks each
  edge_score<<<dim3(5000), 256, 0, stream>>>(cols, qf, kf, aw);
  edge_gather<<<dim3(5000), 256, 0, stream>>>(cols, vf, aw, y);
  // out: 8 * 20 * 4 = 640 blocks; Wob has head-major-permuted input cols
  gemm_o<<<dim3(640), 256, 0, stream>>>(y, Wob, bob, (float*)d_out, NN);
}

// Round 10
// 231.519 us; speedup vs baseline: 1.0692x; 1.0558x over previous
//
#include <hip/hip_runtime.h>
#include <hip/hip_bf16.h>

#define NN 20000
#define DEG 16
#define KD 512      // IN_DIM
#define OD 512      // OUT_DIM
#define NH 4
#define DH 128
#define DROPE 126

#define BM 128
#define BN 128      // gemm_o tile; gemm_k uses BN2=256

typedef unsigned short u16;
typedef unsigned int u32;
typedef __attribute__((ext_vector_type(8))) short short8;
typedef __attribute__((ext_vector_type(4))) float f32x4;

__device__ __forceinline__ float b2f(u16 u){ return __uint_as_float((u32)u << 16); }
__device__ __forceinline__ u16 f2b(float f){
  u32 x = __float_as_uint(f);
  return (u16)((x + 0x7fffu + ((x >> 16) & 1u)) >> 16);   // RNE
}
__device__ __forceinline__ void up8(uint4 u, float* f){
  f[0]=__uint_as_float(u.x<<16); f[1]=__uint_as_float(u.x&0xffff0000u);
  f[2]=__uint_as_float(u.y<<16); f[3]=__uint_as_float(u.y&0xffff0000u);
  f[4]=__uint_as_float(u.z<<16); f[5]=__uint_as_float(u.z&0xffff0000u);
  f[6]=__uint_as_float(u.w<<16); f[7]=__uint_as_float(u.w&0xffff0000u);
}
__device__ __forceinline__ uint4 cvt8(const float* s){
  uint4 a = *(const uint4*)s;
  uint4 b = *(const uint4*)(s + 4);
  uint4 o;
  o.x = (u32)f2b(__uint_as_float(a.x)) | ((u32)f2b(__uint_as_float(a.y)) << 16);
  o.y = (u32)f2b(__uint_as_float(a.z)) | ((u32)f2b(__uint_as_float(a.w)) << 16);
  o.z = (u32)f2b(__uint_as_float(b.x)) | ((u32)f2b(__uint_as_float(b.y)) << 16);
  o.w = (u32)f2b(__uint_as_float(b.z)) | ((u32)f2b(__uint_as_float(b.w)) << 16);
  return o;
}

// async global->LDS, 16B per lane; LDS dest is wave-uniform base + lane*16
__device__ __forceinline__ void load_lds16(const u16* g, u16* l) {
  __builtin_amdgcn_global_load_lds(
      (const __attribute__((address_space(1))) void*)g,
      (__attribute__((address_space(3))) void*)l, 16, 0, 0);
}

// single fused f32->bf16 conversion pass: x (5000 blocks), W x4 (512), biases (1).
// Wo additionally gets its INPUT columns permuted natural->head-major
// (c' = h*128+d reads c = d*4+h) so the final GEMM can consume a head-major y.
struct ConvJob {
  const float* x;  u16* xb;                  // NN*KD
  const float* w[4]; u16* wb[4];             // OD*KD each
  const float* b[4]; u16* bb[4];             // OD each
};
__global__ __launch_bounds__(256) void conv_all(ConvJob j) {
  const int b = blockIdx.x;
  if (b < 5000) {                            // x: 10.24M elems
    const int i8 = (b * 256 + threadIdx.x) * 8;
    *(uint4*)(j.xb + i8) = cvt8(j.x + i8);
  } else if (b < 5512) {                     // weights: 4 x 262144 elems
    const int t = b - 5000;
    const int wsel = t >> 7;                 // 128 blocks per weight
    const int i8 = ((t & 127) * 256 + threadIdx.x) * 8;
    if (wsel < 3) {
      *(uint4*)(j.wb[wsel] + i8) = cvt8(j.w[wsel] + i8);
    } else {
      // Wo permute: output 8 consecutive head-major cols (h fixed, d0..d0+7)
      const int o = i8 >> 9, cp = i8 & 511;
      const int h = cp >> 7, d0 = cp & 127;
      const float* src = j.w[3] + (size_t)o * 512 + h;
      float tmp[8];
      #pragma unroll
      for (int t2 = 0; t2 < 8; t2++) tmp[t2] = src[(size_t)(d0 + t2) * 4];
      uint4 ov;
      ov.x = (u32)f2b(tmp[0]) | ((u32)f2b(tmp[1]) << 16);
      ov.y = (u32)f2b(tmp[2]) | ((u32)f2b(tmp[3]) << 16);
      ov.z = (u32)f2b(tmp[4]) | ((u32)f2b(tmp[5]) << 16);
      ov.w = (u32)f2b(tmp[6]) | ((u32)f2b(tmp[7]) << 16);
      *(uint4*)(j.wb[3] + i8) = ov;
    }
  } else {                                   // biases: 4 x 512 elems in one block
    const int vsel = threadIdx.x >> 6;
    const int i8 = (threadIdx.x & 63) * 8;
    *(uint4*)(j.bb[vsel] + i8) = cvt8(j.b[vsel] + i8);
  }
}

// QKV projection. out[m][o] = sum_k A[m][k]*W[o][k] + bias[o]
// emode 0: q -> scale + rope -> head-major [N][H][DH] bf16 (o0)
// emode 1: k -> rope -> head-major (o1)
// emode 2: v -> head-major, no rope/scale (o2)
// R9 post-mortem: sync-4blk (72.5), dbuf-2blk (68), BK=128-2blk (67.7) ALL
// plateau ~70us at 2 waves/SIMD with MfmaUtil 18 / VALU 33 — too few waves
// to overlap. This round: 512-thread blocks, BM=128 x BN2=256 (wave grid
// 2x4, same 4x4 acc/wave = 64 VGPR), BK=64 single-buffered. 2 blocks/CU but
// 16 waves/CU (4/SIMD, 2x R9). B-reuse doubles; grid 1884->960.
#define BN2 256
__global__ __launch_bounds__(512, 4) void gemm_k(
    const u16* __restrict__ A,
    const u16* __restrict__ W0, const u16* __restrict__ B0,
    const u16* __restrict__ W1, const u16* __restrict__ B1,
    const u16* __restrict__ W2, const u16* __restrict__ B2,
    const float* __restrict__ pos,          // f32! bf16 pos loses 0.2 rad of RoPE angle
    u16* __restrict__ o0, u16* __restrict__ o1, u16* __restrict__ o2,
    int M)
{
  // staging As 16KB + Bs 32KB = 48KB; epilogue Cs [128][4][68]x2B = 69.6KB
  // unions over the dead tiles. 2 blocks/CU.
  __shared__ __align__(16) char smem[69632];
  __shared__ float posS[BM*3];
  __shared__ float freqS[21];               // 10000^(-m/21), m=0..20
  u16* As = (u16*)smem;               // [128 rows][8 chunks], chunk XOR-swizzled
  u16* Bs = As + BM*64;               // [256 rows][8 chunks]

  const int b = blockIdx.x;
  const int xcd = b & 7, rem = b >> 3;      // 960 blocks: 20 rowT x 2 colT x 3 w x 8 xcd
  const int rowT = (rem / 6)*8 + xcd;
  const int sub = rem % 6;
  const int colT = sub & 1, w = sub >> 1;
  if (rowT*BM >= M) return;

  const int tid = threadIdx.x;              // 0..511
  const int wave = tid >> 6, lane = tid & 63;
  const int wr = wave >> 2, wc = wave & 3;  // 2x4 wave grid, 64x64 sub-tiles
  const int lm = lane & 15, lq = lane >> 4;
  const u16* W  = (w == 0) ? W0 : ((w == 1) ? W1 : W2);
  const u16* Bi = (w == 0) ? B0 : ((w == 1) ? B1 : B2);
  const int emode = w;                      // uniform per block
  u16* outQKV = (w == 0) ? o0 : ((w == 1) ? o1 : o2);

  f32x4 acc[4][4];
  #pragma unroll
  for (int i = 0; i < 4; i++)
    #pragma unroll
    for (int jj = 0; jj < 4; jj++)
      acc[i][jj] = (f32x4){0.f, 0.f, 0.f, 0.f};

  // pos/freq staging (covered by first __syncthreads)
  if (emode < 2) {
    if (tid < BM) {
      int gr = rowT*BM + tid; if (gr >= M) gr = M - 1;
      posS[tid*3+0] = pos[gr*3+0];
      posS[tid*3+1] = pos[gr*3+1];
      posS[tid*3+2] = pos[gr*3+2];
    }
    if (tid >= BM && tid < BM + 21)
      freqS[tid - BM] = __expf(-(float)(tid - BM) * 0.43858763676077064f);
  }

  for (int kt = 0; kt < KD; kt += 64) {
    // stage A (1024 chunks, 2 iters) + B (2048 chunks, 4 iters); physical
    // chunk c holds global (row=c>>3, seg=(c&7)^(row&7)); ds_read of
    // (row,seg) -> banks spread 8-way.
    #pragma unroll
    for (int it = 0; it < 2; it++) {
      const int chunk = it*512 + tid;              // 0..1023
      const int row = chunk >> 3, gseg = (chunk & 7) ^ (row & 7);
      int gr = rowT*BM + row; if (gr >= M) gr = M - 1;
      load_lds16(A + (size_t)gr*KD + kt + gseg*8,
                 As + (size_t)(it*512 + wave*64)*8);
    }
    #pragma unroll
    for (int it = 0; it < 4; it++) {
      const int chunk = it*512 + tid;              // 0..2047
      const int row = chunk >> 3, gseg = (chunk & 7) ^ (row & 7);
      load_lds16(W + (size_t)(colT*BN2 + row)*KD + kt + gseg*8,
                 Bs + (size_t)(it*512 + wave*64)*8);
    }
    __syncthreads();                  // drains vmcnt (global_load_lds) too
    #pragma unroll
    for (int kk = 0; kk < 64; kk += 32) {
      const int ks = kk >> 3;                      // 0 or 4
      short8 af[4], bfr[4];
      #pragma unroll
      for (int i = 0; i < 4; i++) {
        const int ra = wr*64 + i*16 + lm;          // 0..127
        af[i] = *(const short8*)(As + (size_t)(ra*8 + ((ks + lq) ^ (ra & 7)))*8);
      }
      #pragma unroll
      for (int i = 0; i < 4; i++) {
        const int rb = wc*64 + i*16 + lm;          // 0..255
        bfr[i] = *(const short8*)(Bs + (size_t)(rb*8 + ((ks + lq) ^ (rb & 7)))*8);
      }
      #pragma unroll
      for (int mi = 0; mi < 4; mi++)
        #pragma unroll
        for (int ni = 0; ni < 4; ni++)
          acc[mi][ni] = __builtin_amdgcn_mfma_f32_16x16x32_bf16(af[mi], bfr[ni], acc[mi][ni], 0, 0, 0);
    }
    __syncthreads();                  // all waves done reading before restage
  }

  float bvv[4];
  #pragma unroll
  for (int ni = 0; ni < 4; ni++)
    bvv[ni] = b2f(Bi[colT*BN2 + wc*64 + ni*16 + lm]);

  u16* Cs = (u16*)smem;   // tiles dead after final barrier

  // emodes 0/1/2: (scale/rope for q,k) then repack to head-major [N][4][128]
  // Cs layout: [rloc 128][h 4][dloc 68(pad)] — tile covers d = colT*64..+63
  #pragma unroll
  for (int mi = 0; mi < 4; mi++) {
    #pragma unroll
    for (int ni = 0; ni < 4; ni++) {
      const int cloc = wc*64 + ni*16 + lm;         // 0..255
      const int h = cloc & 3, dloc = cloc >> 2;    // dloc 0..63
      const int d = colT*64 + dloc;                // 0..127
      #pragma unroll
      for (int r = 0; r < 4; r++) {
        const int rloc = wr*64 + mi*16 + lq*4 + r;
        float v = acc[mi][ni][r] + bvv[ni];
        if (emode == 0) v *= 0.08838834764831845f;  // 1/sqrt(128)
        float vr = v;
        if (emode < 2) {                            // uniform branch per block
          const float partner = __shfl_xor(v, 4);   // rope pair: d ^ 1 == lane ^ 4
          if (d < DROPE) {
            const int pp = d / 42, rem2 = d - pp*42, m = rem2 >> 1, par = rem2 & 1;
            const float ang = posS[rloc*3 + pp] * freqS[m];
            float sn, cs; __sincosf(ang, &sn, &cs);
            vr = par ? (v*cs + partner*sn) : (v*cs - partner*sn);
          }
        }
        Cs[rloc*272 + h*68 + dloc] = f2b(vr);
      }
    }
  }
  __syncthreads();
  #pragma unroll
  for (int pass = 0; pass < 8; pass++) {
    const int c2 = pass*512 + tid;              // 0..4095
    const int dd8 = c2 & 7, h = (c2 >> 3) & 3, rloc = c2 >> 5;
    const int grow = rowT*BM + rloc;
    if (grow < M) {
      uint2 a = *(const uint2*)(Cs + rloc*272 + h*68 + dd8*8);
      uint2 b2 = *(const uint2*)(Cs + rloc*272 + h*68 + dd8*8 + 4);
      *(uint4*)(outQKV + ((size_t)grow*NH + h)*DH + colT*64 + dd8*8)
          = make_uint4(a.x, a.y, b2.x, b2.y);
    }
  }
}

// Out-projection GEMM: y(bf16, head-major-flattened) @ Wo(perm)^T + bo -> f32.
// Single-buffered 32KB LDS (BK=64), no pos/rope/repack, launch_bounds(256,4)
// -> all 640 blocks co-resident.
__global__ __launch_bounds__(256, 4) void gemm_o(
    const u16* __restrict__ A, const u16* __restrict__ W,
    const u16* __restrict__ Bi, float* __restrict__ out, int M)
{
  __shared__ __align__(16) u16 As[BM*64];   // [128 rows][8 chunks], XOR-swizzled
  __shared__ __align__(16) u16 Bs[BN*64];

  const int b = blockIdx.x;
  const int xcd = b & 7, rem = b >> 3;
  const int rowT = (rem >> 2)*8 + xcd, colT = rem & 3;
  if (rowT*BM >= M) return;

  const int tid = threadIdx.x;
  const int wave = tid >> 6, lane = tid & 63;
  const int wr = wave >> 1, wc = wave & 1;
  const int lm = lane & 15, lq = lane >> 4;

  f32x4 acc[4][4];
  #pragma unroll
  for (int i = 0; i < 4; i++)
    #pragma unroll
    for (int jj = 0; jj < 4; jj++)
      acc[i][jj] = (f32x4){0.f, 0.f, 0.f, 0.f};

  for (int kt = 0; kt < KD; kt += 64) {
    #pragma unroll
    for (int it = 0; it < 4; it++) {
      const int chunk = it*256 + wave*64 + lane;     // 0..1023
      const int row = chunk >> 3, gseg = (chunk & 7) ^ (row & 7);
      int gr = rowT*BM + row; if (gr >= M) gr = M - 1;
      load_lds16(A + (size_t)gr*KD + kt + gseg*8,
                 As + (size_t)(it*256 + wave*64)*8);
    }
    #pragma unroll
    for (int it = 0; it < 4; it++) {
      const int chunk = it*256 + wave*64 + lane;
      const int row = chunk >> 3, gseg = (chunk & 7) ^ (row & 7);
      load_lds16(W + (size_t)(colT*BN + row)*KD + kt + gseg*8,
                 Bs + (size_t)(it*256 + wave*64)*8);
    }
    __syncthreads();                  // drains vmcnt (global_load_lds) too
    #pragma unroll
    for (int kk = 0; kk < 64; kk += 32) {
      const int ks = kk >> 3;                      // 0 or 4
      short8 af[4], bfr[4];
      #pragma unroll
      for (int i = 0; i < 4; i++) {
        const int ra = wr*64 + i*16 + lm;
        af[i] = *(const short8*)(As + (size_t)(ra*8 + ((ks + lq) ^ (ra & 7)))*8);
      }
      #pragma unroll
      for (int i = 0; i < 4; i++) {
        const int rb = wc*64 + i*16 + lm;
        bfr[i] = *(const short8*)(Bs + (size_t)(rb*8 + ((ks + lq) ^ (rb & 7)))*8);
      }
      #pragma unroll
      for (int mi = 0; mi < 4; mi++)
        #pragma unroll
        for (int ni = 0; ni < 4; ni++)
          acc[mi][ni] = __builtin_amdgcn_mfma_f32_16x16x32_bf16(af[mi], bfr[ni], acc[mi][ni], 0, 0, 0);
    }
    __syncthreads();
  }

  float bvv[4];
  #pragma unroll
  for (int ni = 0; ni < 4; ni++)
    bvv[ni] = b2f(Bi[colT*BN + wc*64 + ni*16 + lm]);

  // direct f32 stores; 64B segments per lq-group
  #pragma unroll
  for (int mi = 0; mi < 4; mi++)
    #pragma unroll
    for (int ni = 0; ni < 4; ni++) {
      const int Cg = colT*BN + wc*64 + ni*16 + lm;
      #pragma unroll
      for (int r = 0; r < 4; r++) {
        const int grow = rowT*BM + wr*64 + mi*16 + lq*4 + r;
        if (grow < M) out[(size_t)grow*OD + Cg] = acc[mi][ni][r] + bvv[ni];
      }
    }
}

// TWO-PASS head-partitioned edge attention (R5: both passes out of top-5).
// Head-partition: per-XCD hot set k_h or v_h ~5-8MB, near-L2-resident.
// Same (node,head)->XCD mapping in both passes keeps locality consistent.

// pass 1: scores + softmax -> attn weights f32 [N][H][DEG]
__global__ __launch_bounds__(256, 3) void edge_score(
    const int* __restrict__ cols, const u16* __restrict__ qf,
    const u16* __restrict__ kf, float* __restrict__ aw)
{
  const int b = blockIdx.x;
  const int xcd = b & 7;
  const int head = xcd >> 1;
  const int nbase = (b >> 3) * 32 + (xcd & 1) * 16;   // block: 16 nodes, 1 head
  const int wave = threadIdx.x >> 6, lane = threadIdx.x & 63;
  const int g = lane >> 4, l16 = lane & 15;
  const int n = nbase + wave*4 + g;

  const int col = cols[n*DEG + l16];                  // 256B/wave, coalesced
  const uint4 qv = *(const uint4*)(qf + ((size_t)n*NH + head)*DH + l16*8);

  // 16 coalesced 256B k-row loads (per 16-lane group), oldest first
  uint4 kreg[16];
  #pragma unroll
  for (int jj = 0; jj < 16; jj++) {
    const int cj = __shfl(col, g*16 + jj);
    kreg[jj] = *(const uint4*)(kf + ((size_t)cj*NH + head)*DH + l16*8);
  }
  float qa[8]; up8(qv, qa);

  // scores: lane l16 ends holding s[neighbor l16]
  float s = 0.f;
  #pragma unroll
  for (int jj = 0; jj < 16; jj++) {
    float ka[8]; up8(kreg[jj], ka);
    float pr = qa[0]*ka[0] + qa[1]*ka[1] + qa[2]*ka[2] + qa[3]*ka[3]
             + qa[4]*ka[4] + qa[5]*ka[5] + qa[6]*ka[6] + qa[7]*ka[7];
    pr += __shfl_xor(pr, 1);
    pr += __shfl_xor(pr, 2);
    pr += __shfl_xor(pr, 4);
    pr += __shfl_xor(pr, 8);          // full 128-d dot, within the 16-lane group
    s = (l16 == jj) ? pr : s;
  }

  // softmax over the group's 16 lanes
  float mx = s;
  #pragma unroll
  for (int msk = 1; msk < 16; msk <<= 1) mx = fmaxf(mx, __shfl_xor(mx, msk));
  float p = expf(s - mx);
  float dn = p;
  #pragma unroll
  for (int msk = 1; msk < 16; msk <<= 1) dn += __shfl_xor(dn, msk);
  aw[(size_t)(n*NH + head)*DEG + l16] = p / dn;       // 64B per group
}

// pass 2: y[n][h] = sum_j attn[j] * v[col_j][h]
__global__ __launch_bounds__(256, 3) void edge_gather(
    const int* __restrict__ cols, const u16* __restrict__ vf,
    const float* __restrict__ aw, u16* __restrict__ y)
{
  const int b = blockIdx.x;
  const int xcd = b & 7;
  const int head = xcd >> 1;
  const int nbase = (b >> 3) * 32 + (xcd & 1) * 16;
  const int wave = threadIdx.x >> 6, lane = threadIdx.x & 63;
  const int g = lane >> 4, l16 = lane & 15;
  const int n = nbase + wave*4 + g;

  const int col = cols[n*DEG + l16];
  const float a_l = aw[(size_t)(n*NH + head)*DEG + l16];

  uint4 vreg[16];
  #pragma unroll
  for (int jj = 0; jj < 16; jj++) {
    const int cj = __shfl(col, g*16 + jj);
    vreg[jj] = *(const uint4*)(vf + ((size_t)cj*NH + head)*DH + l16*8);
  }

  float ya[8];
  #pragma unroll
  for (int t = 0; t < 8; t++) ya[t] = 0.f;
  #pragma unroll
  for (int jj = 0; jj < 16; jj++) {
    const float a = __shfl(a_l, g*16 + jj);
    float va[8]; up8(vreg[jj], va);
    #pragma unroll
    for (int t = 0; t < 8; t++) ya[t] += a*va[t];
  }
  u32 pk[4];
  #pragma unroll
  for (int t = 0; t < 4; t++)
    pk[t] = (u32)f2b(ya[2*t]) | ((u32)f2b(ya[2*t+1]) << 16);
  *(uint4*)(y + ((size_t)n*NH + head)*DH + l16*8) = make_uint4(pk[0], pk[1], pk[2], pk[3]);
}

extern "C" void kernel_launch(void* const* d_in, const int* in_sizes, int n_in,
                              void* d_out, int out_size, void* d_ws, size_t ws_size,
                              hipStream_t stream) {
  (void)in_sizes; (void)n_in; (void)out_size; (void)ws_size;
  const float* x   = (const float*)d_in[0];
  const float* pos = (const float*)d_in[1];
  // d_in[2] = rows: sorted repeat(arange(N), DEG) — structure used implicitly
  const int* cols = (const int*)d_in[3];
  const float* Wq = (const float*)d_in[4];
  const float* bq = (const float*)d_in[5];
  const float* Wk = (const float*)d_in[6];
  const float* bk = (const float*)d_in[7];
  const float* Wv = (const float*)d_in[8];
  const float* bv = (const float*)d_in[9];
  const float* Wo = (const float*)d_in[10];
  const float* bo = (const float*)d_in[11];

  char* ws = (char*)d_ws;
  size_t off = 0;
  auto carve = [&](size_t bytes) { char* p = ws + off; off += (bytes + 15) & ~(size_t)15; return p; };
  u16* xb   = (u16*)carve((size_t)NN*KD*2);
  u16* Wqb  = (u16*)carve((size_t)OD*KD*2);
  u16* Wkb  = (u16*)carve((size_t)OD*KD*2);
  u16* Wvb  = (u16*)carve((size_t)OD*KD*2);
  u16* Wob  = (u16*)carve((size_t)OD*OD*2);
  u16* bqb  = (u16*)carve((size_t)OD*2);
  u16* bkb  = (u16*)carve((size_t)OD*2);
  u16* bvb  = (u16*)carve((size_t)OD*2);
  u16* bob  = (u16*)carve((size_t)OD*2);
  u16* qf   = (u16*)carve((size_t)NN*OD*2);
  u16* kf   = (u16*)carve((size_t)NN*OD*2);
  u16* vf   = (u16*)carve((size_t)NN*OD*2);
  u16* y    = (u16*)carve((size_t)NN*OD*2);
  float* aw = (float*)carve((size_t)NN*NH*DEG*4);     // attn weights [N][H][DEG]

  ConvJob cj;
  cj.x = x; cj.xb = xb;
  cj.w[0]=Wq; cj.w[1]=Wk; cj.w[2]=Wv; cj.w[3]=Wo;
  cj.wb[0]=Wqb; cj.wb[1]=Wkb; cj.wb[2]=Wvb; cj.wb[3]=Wob;
  cj.b[0]=bq; cj.b[1]=bk; cj.b[2]=bv; cj.b[3]=bo;
  cj.bb[0]=bqb; cj.bb[1]=bkb; cj.bb[2]=bvb; cj.bb[3]=bob;
  conv_all<<<dim3(5513), 256, 0, stream>>>(cj);

  // QKV: 8 xcd * 20 rowT-slots * 6 (colT,w) = 960 blocks (18 early-return)
  gemm_k<<<dim3(960), 512, 0, stream>>>(xb, Wqb, bqb, Wkb, bkb, Wvb, bvb, pos,
                                        qf, kf, vf, NN);
  // two-pass attention: 625 node-chunks * 8 xcd = 5000 blocks each
  edge_score<<<dim3(5000), 256, 0, stream>>>(cols, qf, kf, aw);
  edge_gather<<<dim3(5000), 256, 0, stream>>>(cols, vf, aw, y);
  // out: 8 * 20 * 4 = 640 blocks; Wob has head-major-permuted input cols
  gemm_o<<<dim3(640), 256, 0, stream>>>(y, Wob, bob, (float*)d_out, NN);
}